// Round 1
// baseline (436.621 us; speedup 1.0000x reference)
//
#include <hip/hip_runtime.h>
#include <hip/hip_bf16.h>
#include <math.h>

#define BB   64
#define SS   512
#define NHH  4
#define DD   256
#define HH   256
#define LDH  264   // bf16 LDS row stride (halfwords)

typedef __attribute__((ext_vector_type(8))) short  short8;
typedef __attribute__((ext_vector_type(4))) float  floatx4;

// ---------------------------------------------------------------------------
// ws layout (floats):
//   [0,256)        v2[h]  = W2 @ (Wq @ w2)
//   [256,512)      cb[h'] = bproj @ W1b + bk @ Wc          (Wc = Wproj@W1b)
//   [512]          c2     = b2.v + bq.w2
//   [513]          ck     = bk.w1
//   [768,1024)     qw[b*4+i] carried scalar state
//   [1024,66560)   relu_u at t=511 (256 rows x 256) fp32
//   [66560,132096) packed bf16 weights: W1a at +0, Wd = Wk@Wproj@W1b at +65536
//   [132096,197632) Wc fp32 scratch (init only)
//   [197632,197888) wkw[256] = Wk @ w1
//   [197888,...)   chunk buffers x2: kw Tc*256 fp32 | xw1 Tc*65536 bf16 | kpw Tc*65536 bf16
// ---------------------------------------------------------------------------

__device__ __forceinline__ unsigned short f2b(float f) {
  __hip_bfloat16 h = __float2bfloat16(f);
  return __builtin_bit_cast(unsigned short, h);
}
__device__ __forceinline__ float b2f(unsigned short u) {
  unsigned v = (unsigned)u << 16;
  return __builtin_bit_cast(float, v);
}

// ---------------------------------------------------------------------------
// init1: block 0 = scalar setup; blocks 1..256 = W1a packing;
//        blocks 257..512 = Wc = Wproj @ W1b  (fp32 into ws scratch)
// wpack[mat][panel(16)][ks(8)][lane(64)][j(8)] = W[ks*32+(lane>>4)*8+j][panel*16+(lane&15)]
// ---------------------------------------------------------------------------
__global__ __launch_bounds__(256) void init1_kernel(
    const float* __restrict__ Wk, const float* __restrict__ Wproj,
    const float* __restrict__ W1, const float* __restrict__ Wq,
    const float* __restrict__ bq, const float* __restrict__ w_mlp,
    const float* __restrict__ W2, const float* __restrict__ b2,
    const float* __restrict__ bk,
    float* __restrict__ ws, unsigned short* __restrict__ wpack)
{
  __shared__ float vsh[256];
  __shared__ float red[256];
  int tid = threadIdx.x;
  int b = blockIdx.x;

  if (b == 0) {
    const float* w2 = w_mlp + HH;
    // v[h] = Wq[h,:] . w2
    {
      float a = 0.f;
      const float4* Wq4 = (const float4*)(Wq + tid * 256);
      const float4* w24 = (const float4*)w2;
      for (int k = 0; k < 64; ++k) {
        float4 wv = Wq4[k], xv = w24[k];
        a = fmaf(wv.x, xv.x, fmaf(wv.y, xv.y, fmaf(wv.z, xv.z, fmaf(wv.w, xv.w, a))));
      }
      vsh[tid] = a;
    }
    __syncthreads();
    // v2[h] = W2[h,:] . v
    {
      float a2 = 0.f;
      const float4* W24 = (const float4*)(W2 + tid * 256);
      const float4* v4  = (const float4*)vsh;
      for (int k = 0; k < 64; ++k) {
        float4 wv = W24[k], xv = v4[k];
        a2 = fmaf(wv.x, xv.x, fmaf(wv.y, xv.y, fmaf(wv.z, xv.z, fmaf(wv.w, xv.w, a2))));
      }
      ws[tid] = a2;
    }
    // c = bq . w2
    red[tid] = bq[tid] * w_mlp[HH + tid];
    __syncthreads();
    for (int s = 128; s; s >>= 1) { if (tid < s) red[tid] += red[tid + s]; __syncthreads(); }
    float c = red[0];
    __syncthreads();
    ws[768 + tid] = c;                 // qw init for all 256 (b,i) chains
    // c2 = b2.v + c
    red[tid] = b2[tid] * vsh[tid];
    __syncthreads();
    for (int s = 128; s; s >>= 1) { if (tid < s) red[tid] += red[tid + s]; __syncthreads(); }
    if (tid == 0) ws[512] = red[0] + c;
    __syncthreads();
    // ck = bk . w1
    red[tid] = bk[tid] * w_mlp[tid];
    __syncthreads();
    for (int s = 128; s; s >>= 1) { if (tid < s) red[tid] += red[tid + s]; __syncthreads(); }
    if (tid == 0) ws[513] = red[0];
    return;
  }

  if (b <= 256) {
    // pack W1a (= W1[0:256,:]) as mat 0
    int idx = (b - 1) * 256 + tid;     // 0..65535
    int j    = idx & 7;
    int lane = (idx >> 3) & 63;
    int ks   = (idx >> 9) & 7;
    int pan  = idx >> 12;
    int k = ks * 32 + ((lane >> 4) << 3) + j;
    int n = pan * 16 + (lane & 15);
    wpack[idx] = f2b(W1[k * 256 + n]);
    return;
  }

  // Wc row r: Wc[r,n] = sum_k Wproj[r,k] * W1b[k,n]
  {
    int r = b - 257;
    const float* w1b = W1 + 256 * 256;
    float acc = 0.f;
    for (int k = 0; k < 256; ++k)
      acc = fmaf(Wproj[r * 256 + k], w1b[k * 256 + tid], acc);
    ws[132096 + r * 256 + tid] = acc;
  }
}

// ---------------------------------------------------------------------------
// init2: blocks 0..255 = Wd = Wk @ Wc (fp32), packed bf16 directly as mat 1;
//        also wkw[r] = Wk[r,:].w1. Block 256 = cb' = bproj@W1b + bk@Wc.
// ---------------------------------------------------------------------------
__global__ __launch_bounds__(256) void init2_kernel(
    const float* __restrict__ Wk, const float* __restrict__ W1,
    const float* __restrict__ bproj, const float* __restrict__ bk,
    const float* __restrict__ w_mlp,
    float* __restrict__ ws, unsigned short* __restrict__ wpack)
{
  __shared__ float red[256];
  int tid = threadIdx.x;
  int b = blockIdx.x;
  const float* Wc = ws + 132096;

  if (b < 256) {
    int r = b;
    float acc = 0.f;
    for (int k = 0; k < 256; ++k)
      acc = fmaf(Wk[r * 256 + k], Wc[k * 256 + tid], acc);
    // scatter-pack element (k=r, n=tid) into mat 1
    int n = tid;
    int pan = n >> 4, ks = r >> 5, j = r & 7;
    int lane = ((r >> 3) & 3) * 16 + (n & 15);
    wpack[65536 + pan * 4096 + ks * 512 + lane * 8 + j] = f2b(acc);
    // wkw[r] = Wk[r,:].w1
    red[tid] = Wk[r * 256 + tid] * w_mlp[tid];
    __syncthreads();
    for (int s = 128; s; s >>= 1) { if (tid < s) red[tid] += red[tid + s]; __syncthreads(); }
    if (tid == 0) ws[197632 + r] = red[0];
    return;
  }

  // cb'[n] = bproj@W1b + bk@Wc
  {
    const float* w1b = W1 + 256 * 256;
    float a3 = 0.f;
    for (int k = 0; k < 256; ++k)
      a3 = fmaf(bproj[k], w1b[k * 256 + tid], a3);
    for (int k = 0; k < 256; ++k)
      a3 = fmaf(bk[k], Wc[k * 256 + tid], a3);
    ws[256 + tid] = a3;
  }
}

// ---------------------------------------------------------------------------
// 64x256 (K=256) bf16 MFMA GEMM, 4x B-reuse: wave w owns n-panels [w*4,w*4+4),
// loops all 4 m-fragments from LDS. acc[mf][pp]. Depth-2 B / depth-1 A prefetch.
// ---------------------------------------------------------------------------
__device__ __forceinline__ void mfma_gemm4(
    const unsigned short* A_lds, const short8* __restrict__ Bp,
    const float* __restrict__ bias, floatx4 acc[4][4], int l, int w)
{
  int col = l & 15, quad = l >> 4;
#pragma unroll
  for (int pp = 0; pp < 4; ++pp) {
    float bv = bias ? bias[(w * 4 + pp) * 16 + col] : 0.f;
#pragma unroll
    for (int mf = 0; mf < 4; ++mf)
      acc[mf][pp] = (floatx4){bv, bv, bv, bv};
  }
  const short8* Bb = Bp + (size_t)(w * 4) * 512 + l;   // panel stride = 8*64 short8
  short8 bb[3][4];
  short8 aa[2][4];
#pragma unroll
  for (int pp = 0; pp < 4; ++pp) bb[0][pp] = Bb[pp * 512];
#pragma unroll
  for (int pp = 0; pp < 4; ++pp) bb[1][pp] = Bb[pp * 512 + 64];
#pragma unroll
  for (int mf = 0; mf < 4; ++mf)
    aa[0][mf] = *(const short8*)(A_lds + (mf * 16 + col) * LDH + quad * 8);
#pragma unroll
  for (int kb = 0; kb < 8; ++kb) {
    if (kb + 2 < 8) {
#pragma unroll
      for (int pp = 0; pp < 4; ++pp)
        bb[(kb + 2) % 3][pp] = Bb[pp * 512 + (kb + 2) * 64];
    }
    if (kb + 1 < 8) {
#pragma unroll
      for (int mf = 0; mf < 4; ++mf)
        aa[(kb + 1) & 1][mf] =
            *(const short8*)(A_lds + (mf * 16 + col) * LDH + (kb + 1) * 32 + quad * 8);
    }
#pragma unroll
    for (int mf = 0; mf < 4; ++mf)
#pragma unroll
      for (int pp = 0; pp < 4; ++pp)
        acc[mf][pp] = __builtin_amdgcn_mfma_f32_16x16x32_bf16(
            aa[kb & 1][mf], bb[kb % 3][pp], acc[mf][pp], 0, 0, 0);
  }
}

// acc -> global bf16, layout [tc][b][head][256]
__device__ __forceinline__ void acc_to_global(
    unsigned short* __restrict__ dst, const floatx4 acc[4][4],
    int l, int w, int b, int tt)
{
  int col = l & 15, quad = l >> 4;
#pragma unroll
  for (int mf = 0; mf < 4; ++mf)
#pragma unroll
    for (int r = 0; r < 4; ++r) {
      int m2 = mf * 16 + quad * 4 + r;
      size_t base = (((size_t)(tt * 16 + (m2 >> 2)) * 64 + b) * 4 + (m2 & 3)) * 256;
#pragma unroll
      for (int pp = 0; pp < 4; ++pp)
        dst[base + (w * 4 + pp) * 16 + col] = f2b(acc[mf][pp][r]);
    }
}

// ---------------------------------------------------------------------------
// precompute: stage X once; two independent GEMMs off the same A tile
//   xw1 = X@W1a + b1 ;  kpw = X@Wd ;  kw = X.wkw + ck
// ---------------------------------------------------------------------------
__device__ void precompute_block(
    int px, const float* __restrict__ x, const unsigned short* __restrict__ wpack,
    const float* __restrict__ b1, const float* __restrict__ ws,
    float* __restrict__ kw_c, unsigned short* __restrict__ xw1_c,
    unsigned short* __restrict__ kpw_c, int t0, char* smem)
{
  float* kwbuf = (float*)smem;                              // [64][4] fp32
  unsigned short* XS = (unsigned short*)(smem + 2048);      // [64][LDH] bf16

  int b  = px & 63;
  int tt = px >> 6;
  int tid = threadIdx.x;
  int l = tid & 63, w = tid >> 6;

  // stage X (64x256 fp32 -> bf16 LDS), coalesced
  const float4* xsrc = (const float4*)(x + (size_t)(b * SS + t0 + tt * 16) * NHH * DD);
#pragma unroll
  for (int i = 0; i < 16; ++i) {
    int f4 = i * 256 + tid;
    int r = f4 >> 6, c4 = f4 & 63;
    float4 v = xsrc[f4];
    ushort4 h;
    h.x = f2b(v.x); h.y = f2b(v.y); h.z = f2b(v.z); h.w = f2b(v.w);
    *(ushort4*)&XS[r * LDH + c4 * 4] = h;
  }
  __syncthreads();

  const short8* wpA = (const short8*)(wpack);               // W1a
  const short8* wpD = (const short8*)(wpack + 65536);       // Wd

  // kw partials: wave w covers cols [w*64, w*64+64), row = l, from XS
  {
    const float* wkw = ws + 197632;
    float part = 0.f;
    const unsigned short* trow = XS + l * LDH + w * 64;
#pragma unroll
    for (int j8 = 0; j8 < 8; ++j8) {
      short8 tv = *(const short8*)(trow + j8 * 8);
#pragma unroll
      for (int j = 0; j < 8; ++j)
        part = fmaf(b2f((unsigned short)tv[j]), wkw[w * 64 + j8 * 8 + j], part);
    }
    kwbuf[l * 4 + w] = part;
  }

  floatx4 acc[4][4];

  // GEMM 1: xw1 = X@W1a + b1 -> global bf16
  mfma_gemm4(XS, wpA, b1, acc, l, w);
  acc_to_global(xw1_c, acc, l, w, b, tt);

  // GEMM 2: kpw = X@Wd -> global bf16
  mfma_gemm4(XS, wpD, nullptr, acc, l, w);
  acc_to_global(kpw_c, acc, l, w, b, tt);

  __syncthreads();   // kwbuf complete
  if (tid < 64) {
    float s = kwbuf[tid * 4] + kwbuf[tid * 4 + 1] + kwbuf[tid * 4 + 2] + kwbuf[tid * 4 + 3]
            + ws[513];
    kw_c[((size_t)(tt * 16 + (tid >> 2)) * 64 + b) * 4 + (tid & 3)] = s;
  }
}

// ---------------------------------------------------------------------------
__device__ __forceinline__ float wave_reduce_sum(float x) {
#define DPPSTEP(ctrl, rmask)                                                   \
  {                                                                            \
    int _s = __builtin_amdgcn_update_dpp(0, __builtin_bit_cast(int, x),        \
                                         (ctrl), (rmask), 0xf, true);          \
    x += __builtin_bit_cast(float, _s);                                        \
  }
  DPPSTEP(0x111, 0xf)   // row_shr:1
  DPPSTEP(0x112, 0xf)   // row_shr:2
  DPPSTEP(0x114, 0xf)   // row_shr:4
  DPPSTEP(0x118, 0xf)   // row_shr:8
  DPPSTEP(0x142, 0xa)   // row_bcast15
  DPPSTEP(0x143, 0xc)   // row_bcast31
#undef DPPSTEP
  return __builtin_bit_cast(float, __builtin_amdgcn_readlane(__builtin_bit_cast(int, x), 63));
}

__device__ __forceinline__ float tanh_fast(float y) {
  float ex = __expf(2.f * y);
  return 1.f - 2.f * __builtin_amdgcn_rcpf(ex + 1.f);
}

// ---------------------------------------------------------------------------
__device__ void seq_block(
    const unsigned short* __restrict__ xw1_c, const unsigned short* __restrict__ kpw_c,
    const float* __restrict__ kw_c, float* __restrict__ ws,
    float* __restrict__ relu_u, int t0, int n)
{
  int b = blockIdx.x;
  int tid = threadIdx.x;
  int i = tid >> 6, l = tid & 63;

  float4 v2v = ((const float4*)ws)[l];
  float4 cbv = ((const float4*)(ws + 256))[l];
  float c2 = ws[512];
  float qw = ws[768 + b * 4 + i];

  const ushort4* xw = (const ushort4*)xw1_c;
  const ushort4* kp = (const ushort4*)kpw_c;

  struct Slot { ushort4 x, k0, k1, k2, k3; float4 kw; };

  auto load = [&](Slot& s, int tc) {
    size_t rb_ = (size_t)(tc * 64 + b) * 4;
    s.x  = xw[(rb_ + i) * 64 + l];
    s.k0 = kp[(rb_ + 0) * 64 + l];
    s.k1 = kp[(rb_ + 1) * 64 + l];
    s.k2 = kp[(rb_ + 2) * 64 + l];
    s.k3 = kp[(rb_ + 3) * 64 + l];
    s.kw = *(const float4*)&kw_c[rb_];
  };

  auto step = [&](Slot& s, int t) {
    float e0 = tanh_fast(qw + s.kw.x);
    float e1 = tanh_fast(qw + s.kw.y);
    float e2 = tanh_fast(qw + s.kw.z);
    float e3 = tanh_fast(qw + s.kw.w);
    float q0 = __expf(e0), q1 = __expf(e1), q2 = __expf(e2), q3 = __expf(e3);
    float inv = __builtin_amdgcn_rcpf(q0 + q1 + q2 + q3);
    float4 K0 = {b2f(s.k0.x), b2f(s.k0.y), b2f(s.k0.z), b2f(s.k0.w)};
    float4 K1 = {b2f(s.k1.x), b2f(s.k1.y), b2f(s.k1.z), b2f(s.k1.w)};
    float4 K2 = {b2f(s.k2.x), b2f(s.k2.y), b2f(s.k2.z), b2f(s.k2.w)};
    float4 K3 = {b2f(s.k3.x), b2f(s.k3.y), b2f(s.k3.z), b2f(s.k3.w)};
    float4 X  = {b2f(s.x.x) + cbv.x, b2f(s.x.y) + cbv.y,
                 b2f(s.x.z) + cbv.z, b2f(s.x.w) + cbv.w};
    float4 a;
    a.x = fmaf(q0, K0.x, fmaf(q1, K1.x, fmaf(q2, K2.x, q3 * K3.x)));
    a.y = fmaf(q0, K0.y, fmaf(q1, K1.y, fmaf(q2, K2.y, q3 * K3.y)));
    a.z = fmaf(q0, K0.z, fmaf(q1, K1.z, fmaf(q2, K2.z, q3 * K3.z)));
    a.w = fmaf(q0, K0.w, fmaf(q1, K1.w, fmaf(q2, K2.w, q3 * K3.w)));
    float4 u;
    u.x = fmaf(a.x, inv, X.x); u.y = fmaf(a.y, inv, X.y);
    u.z = fmaf(a.z, inv, X.z); u.w = fmaf(a.w, inv, X.w);
    float4 r;
    r.x = fmaxf(u.x, 0.f); r.y = fmaxf(u.y, 0.f);
    r.z = fmaxf(u.z, 0.f); r.w = fmaxf(u.w, 0.f);
    float d = fmaf(r.x, v2v.x, fmaf(r.y, v2v.y, fmaf(r.z, v2v.z, r.w * v2v.w)));
    qw = wave_reduce_sum(d) + c2;
    if (t0 + t == SS - 1)
      *(float4*)&relu_u[(size_t)(b * 4 + i) * 256 + l * 4] = r;
  };

  Slot s0, s1, s2, s3;
  load(s0, 0); load(s1, 1); load(s2, 2); load(s3, 3);
  for (int t = 0; t < n; t += 4) {
    int nt;
    step(s0, t);     nt = t + 4; load(s0, nt < n ? nt : n - 1);
    step(s1, t + 1); nt = t + 5; load(s1, nt < n ? nt : n - 1);
    step(s2, t + 2); nt = t + 6; load(s2, nt < n ? nt : n - 1);
    step(s3, t + 3); nt = t + 7; load(s3, nt < n ? nt : n - 1);
  }
  if (l == 0) ws[768 + b * 4 + i] = qw;
}

// ---------------------------------------------------------------------------
// Fused: blocks [0,64) = seq chunk (prev buffer), blocks [64,..) = precompute
// ---------------------------------------------------------------------------
__global__ __launch_bounds__(256, 2) void fused_kernel(
    const float* __restrict__ x, const unsigned short* __restrict__ wpack,
    const float* __restrict__ b1,
    float* kwB, unsigned short* xw1B, unsigned short* kpwB, int t0_pre,
    const float* kwA, const unsigned short* xw1A, const unsigned short* kpwA,
    int t0_seq, int n_seq,
    float* __restrict__ ws, float* __restrict__ relu_u)
{
  __shared__ __align__(16) char smem[2048 + 64 * LDH * 2];
  if (blockIdx.x < 64) {
    if (n_seq > 0) seq_block(xw1A, kpwA, kwA, ws, relu_u, t0_seq, n_seq);
    return;
  }
  precompute_block(blockIdx.x - 64, x, wpack, b1, ws,
                   kwB, xw1B, kpwB, t0_pre, smem);
}

// ---------------------------------------------------------------------------
__global__ __launch_bounds__(256) void final_hidden_kernel(
    const float* __restrict__ relu_u, const float* __restrict__ W2,
    const float* __restrict__ b2, float* __restrict__ out)
{
  __shared__ float rs[256];
  int row = blockIdx.x;
  int tid = threadIdx.x;
  rs[tid] = relu_u[(size_t)row * 256 + tid];
  __syncthreads();
  float acc = b2[tid];
  for (int k = 0; k < 256; ++k) acc = fmaf(rs[k], W2[k * 256 + tid], acc);
  out[192 + (size_t)row * 256 + tid] = acc;
}

__global__ __launch_bounds__(256) void final_logits_kernel(
    const float* __restrict__ hf, const float* __restrict__ Wo,
    const float* __restrict__ bo, float* __restrict__ outp)
{
  __shared__ float r0[256], r1[256], r2[256];
  int b = blockIdx.x;
  int tid = threadIdx.x;
  float a0 = 0.f, a1 = 0.f, a2 = 0.f;
  for (int k = tid; k < 1024; k += 256) {
    float h = hf[(size_t)b * 1024 + k];
    a0 = fmaf(h, Wo[k * 3 + 0], a0);
    a1 = fmaf(h, Wo[k * 3 + 1], a1);
    a2 = fmaf(h, Wo[k * 3 + 2], a2);
  }
  r0[tid] = a0; r1[tid] = a1; r2[tid] = a2;
  __syncthreads();
  for (int s = 128; s; s >>= 1) {
    if (tid < s) { r0[tid] += r0[tid + s]; r1[tid] += r1[tid + s]; r2[tid] += r2[tid + s]; }
    __syncthreads();
  }
  if (tid == 0) {
    float l0 = r0[0] + bo[0], l1 = r1[0] + bo[1], l2 = r2[0] + bo[2];
    float m = fmaxf(l0, fmaxf(l1, l2));
    float lse = m + logf(expf(l0 - m) + expf(l1 - m) + expf(l2 - m));
    outp[b * 3 + 0] = l0 - lse;
    outp[b * 3 + 1] = l1 - lse;
    outp[b * 3 + 2] = l2 - lse;
  }
}

// ---------------------------------------------------------------------------
extern "C" void kernel_launch(void* const* d_in, const int* in_sizes, int n_in,
                              void* d_out, int out_size, void* d_ws, size_t ws_size,
                              hipStream_t stream)
{
  const float* x     = (const float*)d_in[0];
  const float* Wk    = (const float*)d_in[1];
  const float* bk    = (const float*)d_in[2];
  const float* Wq    = (const float*)d_in[3];
  const float* bq    = (const float*)d_in[4];
  const float* w_mlp = (const float*)d_in[5];
  const float* Wproj = (const float*)d_in[6];
  const float* bproj = (const float*)d_in[7];
  const float* W1    = (const float*)d_in[8];
  const float* b1    = (const float*)d_in[9];
  const float* W2    = (const float*)d_in[10];
  const float* b2    = (const float*)d_in[11];
  const float* Wo    = (const float*)d_in[12];
  const float* bo    = (const float*)d_in[13];
  float* out = (float*)d_out;
  float* ws  = (float*)d_ws;

  float* ru = ws + 1024;
  unsigned short* wpack = (unsigned short*)(ws + 66560);
  const size_t OFF_CH = 197888;                      // floats
  const long per_t = 256 + 65536;                    // floats per timestep

  long ws_floats = (long)(ws_size / 4);
  long avail = ws_floats - (long)OFF_CH;

  int Tc = 128;
  while (Tc > 0 && 2L * Tc * per_t > avail) Tc -= 16;
  bool pipelined = (Tc >= 16);
  if (!pipelined) {
    Tc = 128;
    while (Tc > 16 && (long)Tc * per_t > avail) Tc -= 16;
  }

  float* bufA = ws + OFF_CH;
  float* bufB = pipelined ? bufA + (size_t)Tc * per_t : bufA;

  auto kw_of  = [&](float* base) { return base; };
  auto xw_of  = [&](float* base) { return (unsigned short*)(base + (size_t)Tc * 256); };
  auto kpw_of = [&](float* base) { return (unsigned short*)(base + (size_t)Tc * 256) + (size_t)Tc * 65536; };

  init1_kernel<<<513, 256, 0, stream>>>(Wk, Wproj, W1, Wq, bq, w_mlp, W2, b2, bk,
                                        ws, wpack);
  init2_kernel<<<257, 256, 0, stream>>>(Wk, W1, bproj, bk, w_mlp, ws, wpack);

  int C = (SS + Tc - 1) / Tc;

  if (pipelined) {
    for (int r = 0; r <= C; ++r) {
      bool hasPre = (r < C);
      bool hasSeq = (r >= 1);
      int t0p = r * Tc;
      int np  = hasPre ? ((SS - t0p) < Tc ? (SS - t0p) : Tc) : 0;
      int t0s = (r - 1) * Tc;
      int ns  = hasSeq ? ((SS - t0s) < Tc ? (SS - t0s) : Tc) : 0;
      float* pB = ((r & 1) ? bufB : bufA);
      float* pA = (((r - 1) & 1) ? bufB : bufA);
      int grid = 64 + (hasPre ? 64 * (np / 16) : 0);
      fused_kernel<<<grid, 256, 0, stream>>>(
          x, wpack, b1,
          kw_of(pB), xw_of(pB), kpw_of(pB), t0p,
          kw_of(pA), xw_of(pA), kpw_of(pA), t0s, ns,
          ws, ru);
    }
  } else {
    for (int c = 0; c < C; ++c) {
      int t0 = c * Tc;
      int n = (SS - t0) < Tc ? (SS - t0) : Tc;
      fused_kernel<<<64 + 64 * (n / 16), 256, 0, stream>>>(
          x, wpack, b1,
          kw_of(bufA), xw_of(bufA), kpw_of(bufA), t0,
          kw_of(bufA), xw_of(bufA), kpw_of(bufA), 0, 0,
          ws, ru);
      fused_kernel<<<64, 256, 0, stream>>>(
          x, wpack, b1,
          kw_of(bufA), xw_of(bufA), kpw_of(bufA), t0,
          kw_of(bufA), xw_of(bufA), kpw_of(bufA), t0, n,
          ws, ru);
    }
  }

  final_hidden_kernel<<<BB * NHH, 256, 0, stream>>>(ru, W2, b2, out);
  final_logits_kernel<<<BB, 256, 0, stream>>>(out + 192, Wo, bo, out);
}

// Round 3
// 412.097 us; speedup vs baseline: 1.0595x; 1.0595x over previous
//
#include <hip/hip_runtime.h>
#include <hip/hip_bf16.h>
#include <math.h>

#define BB   64
#define SS   512
#define NHH  4
#define DD   256
#define HH   256
#define LDH  264   // bf16 LDS row stride (halfwords)

typedef __attribute__((ext_vector_type(8))) short  short8;
typedef __attribute__((ext_vector_type(4))) float  floatx4;

// ---------------------------------------------------------------------------
// ws layout (floats):
//   [0,256)        v2s[h] = 2 * W2 @ (Wq @ w2)                (prescaled x2)
//   [256,512)      cb[h'] = bproj @ W1b + bk @ Wc             (Wc = Wproj@W1b)
//   [512]          c2s    = 2*(b2.v + bq.w2)                  (prescaled x2)
//   [513]          cks    = 2*(bk.w1)                         (prescaled x2)
//   [768,1024)     qw2[b*4+i] carried scalar state (2x domain)
//   [1024,66560)   relu_u at t=511 (256 rows x 256) fp32
//   [66560,132096) packed bf16 weights: W1a at +0, Wd = Wk@Wproj@W1b at +65536
//   [132096,197632) Wc fp32 scratch (init only)
//   [197632,197888) wkws[256] = 2 * Wk @ w1                   (prescaled x2)
//   [197888,198144) biasX[256] = b1 + cb
//   [198144,...)   chunk buffers x2: kw Tc*256 f32 | xw1 Tc*65536 f32 | kpw Tc*65536 f32
// ---------------------------------------------------------------------------

__device__ __forceinline__ unsigned short f2b(float f) {
  __hip_bfloat16 h = __float2bfloat16(f);
  return __builtin_bit_cast(unsigned short, h);
}
__device__ __forceinline__ float b2f(unsigned short u) {
  unsigned v = (unsigned)u << 16;
  return __builtin_bit_cast(float, v);
}

// ---------------------------------------------------------------------------
// init1: block 0 = scalar setup; blocks 1..256 = W1a packing;
//        blocks 257..512 = Wc = Wproj @ W1b  (fp32 into ws scratch)
// wpack[mat][panel(16)][ks(8)][lane(64)][j(8)] = W[ks*32+(lane>>4)*8+j][panel*16+(lane&15)]
// ---------------------------------------------------------------------------
__global__ __launch_bounds__(256) void init1_kernel(
    const float* __restrict__ Wk, const float* __restrict__ Wproj,
    const float* __restrict__ W1, const float* __restrict__ Wq,
    const float* __restrict__ bq, const float* __restrict__ w_mlp,
    const float* __restrict__ W2, const float* __restrict__ b2,
    const float* __restrict__ bk,
    float* __restrict__ ws, unsigned short* __restrict__ wpack)
{
  __shared__ float vsh[256];
  __shared__ float red[256];
  int tid = threadIdx.x;
  int b = blockIdx.x;

  if (b == 0) {
    const float* w2 = w_mlp + HH;
    // v[h] = Wq[h,:] . w2
    {
      float a = 0.f;
      const float4* Wq4 = (const float4*)(Wq + tid * 256);
      const float4* w24 = (const float4*)w2;
      for (int k = 0; k < 64; ++k) {
        float4 wv = Wq4[k], xv = w24[k];
        a = fmaf(wv.x, xv.x, fmaf(wv.y, xv.y, fmaf(wv.z, xv.z, fmaf(wv.w, xv.w, a))));
      }
      vsh[tid] = a;
    }
    __syncthreads();
    // v2s[h] = 2 * W2[h,:] . v
    {
      float a2 = 0.f;
      const float4* W24 = (const float4*)(W2 + tid * 256);
      const float4* v4  = (const float4*)vsh;
      for (int k = 0; k < 64; ++k) {
        float4 wv = W24[k], xv = v4[k];
        a2 = fmaf(wv.x, xv.x, fmaf(wv.y, xv.y, fmaf(wv.z, xv.z, fmaf(wv.w, xv.w, a2))));
      }
      ws[tid] = 2.f * a2;
    }
    // c = bq . w2
    red[tid] = bq[tid] * w_mlp[HH + tid];
    __syncthreads();
    for (int s = 128; s; s >>= 1) { if (tid < s) red[tid] += red[tid + s]; __syncthreads(); }
    float c = red[0];
    __syncthreads();
    ws[768 + tid] = 2.f * c;           // qw2 init for all 256 (b,i) chains
    // c2s = 2*(b2.v + c)
    red[tid] = b2[tid] * vsh[tid];
    __syncthreads();
    for (int s = 128; s; s >>= 1) { if (tid < s) red[tid] += red[tid + s]; __syncthreads(); }
    if (tid == 0) ws[512] = 2.f * (red[0] + c);
    __syncthreads();
    // cks = 2*(bk . w1)
    red[tid] = bk[tid] * w_mlp[tid];
    __syncthreads();
    for (int s = 128; s; s >>= 1) { if (tid < s) red[tid] += red[tid + s]; __syncthreads(); }
    if (tid == 0) ws[513] = 2.f * red[0];
    return;
  }

  if (b <= 256) {
    // pack W1a (= W1[0:256,:]) as mat 0
    int idx = (b - 1) * 256 + tid;     // 0..65535
    int j    = idx & 7;
    int lane = (idx >> 3) & 63;
    int ks   = (idx >> 9) & 7;
    int pan  = idx >> 12;
    int k = ks * 32 + ((lane >> 4) << 3) + j;
    int n = pan * 16 + (lane & 15);
    wpack[idx] = f2b(W1[k * 256 + n]);
    return;
  }

  // Wc row r: Wc[r,n] = sum_k Wproj[r,k] * W1b[k,n]
  {
    int r = b - 257;
    const float* w1b = W1 + 256 * 256;
    float acc = 0.f;
    for (int k = 0; k < 256; ++k)
      acc = fmaf(Wproj[r * 256 + k], w1b[k * 256 + tid], acc);
    ws[132096 + r * 256 + tid] = acc;
  }
}

// ---------------------------------------------------------------------------
// init2: blocks 0..255 = Wd = Wk @ Wc (fp32), packed bf16 directly as mat 1;
//        also wkws[r] = 2*Wk[r,:].w1. Block 256 = cb + biasX.
// ---------------------------------------------------------------------------
__global__ __launch_bounds__(256) void init2_kernel(
    const float* __restrict__ Wk, const float* __restrict__ W1,
    const float* __restrict__ bproj, const float* __restrict__ bk,
    const float* __restrict__ w_mlp, const float* __restrict__ b1,
    float* __restrict__ ws, unsigned short* __restrict__ wpack)
{
  __shared__ float red[256];
  int tid = threadIdx.x;
  int b = blockIdx.x;
  const float* Wc = ws + 132096;

  if (b < 256) {
    int r = b;
    float acc = 0.f;
    for (int k = 0; k < 256; ++k)
      acc = fmaf(Wk[r * 256 + k], Wc[k * 256 + tid], acc);
    // scatter-pack element (k=r, n=tid) into mat 1
    int n = tid;
    int pan = n >> 4, ks = r >> 5, j = r & 7;
    int lane = ((r >> 3) & 3) * 16 + (n & 15);
    wpack[65536 + pan * 4096 + ks * 512 + lane * 8 + j] = f2b(acc);
    // wkws[r] = 2 * Wk[r,:].w1
    red[tid] = Wk[r * 256 + tid] * w_mlp[tid];
    __syncthreads();
    for (int s = 128; s; s >>= 1) { if (tid < s) red[tid] += red[tid + s]; __syncthreads(); }
    if (tid == 0) ws[197632 + r] = 2.f * red[0];
    return;
  }

  // cb[n] = bproj@W1b + bk@Wc ; biasX[n] = b1[n] + cb[n]
  {
    const float* w1b = W1 + 256 * 256;
    float a3 = 0.f;
    for (int k = 0; k < 256; ++k)
      a3 = fmaf(bproj[k], w1b[k * 256 + tid], a3);
    for (int k = 0; k < 256; ++k)
      a3 = fmaf(bk[k], Wc[k * 256 + tid], a3);
    ws[256 + tid] = a3;
    ws[197888 + tid] = a3 + b1[tid];
  }
}

// ---------------------------------------------------------------------------
// 64x256 (K=256) bf16 MFMA GEMM, 4x B-reuse: wave w owns n-panels [w*4,w*4+4),
// loops all 4 m-fragments from LDS. acc[mf][pp]. Depth-2 B / depth-1 A prefetch.
// ---------------------------------------------------------------------------
__device__ __forceinline__ void mfma_gemm4(
    const unsigned short* A_lds, const short8* __restrict__ Bp,
    const float* __restrict__ bias, floatx4 acc[4][4], int l, int w)
{
  int col = l & 15, quad = l >> 4;
#pragma unroll
  for (int pp = 0; pp < 4; ++pp) {
    float bv = bias ? bias[(w * 4 + pp) * 16 + col] : 0.f;
#pragma unroll
    for (int mf = 0; mf < 4; ++mf)
      acc[mf][pp] = (floatx4){bv, bv, bv, bv};
  }
  const short8* Bb = Bp + (size_t)(w * 4) * 512 + l;   // panel stride = 8*64 short8
  short8 bb[3][4];
  short8 aa[2][4];
#pragma unroll
  for (int pp = 0; pp < 4; ++pp) bb[0][pp] = Bb[pp * 512];
#pragma unroll
  for (int pp = 0; pp < 4; ++pp) bb[1][pp] = Bb[pp * 512 + 64];
#pragma unroll
  for (int mf = 0; mf < 4; ++mf)
    aa[0][mf] = *(const short8*)(A_lds + (mf * 16 + col) * LDH + quad * 8);
#pragma unroll
  for (int kb = 0; kb < 8; ++kb) {
    if (kb + 2 < 8) {
#pragma unroll
      for (int pp = 0; pp < 4; ++pp)
        bb[(kb + 2) % 3][pp] = Bb[pp * 512 + (kb + 2) * 64];
    }
    if (kb + 1 < 8) {
#pragma unroll
      for (int mf = 0; mf < 4; ++mf)
        aa[(kb + 1) & 1][mf] =
            *(const short8*)(A_lds + (mf * 16 + col) * LDH + (kb + 1) * 32 + quad * 8);
    }
#pragma unroll
    for (int mf = 0; mf < 4; ++mf)
#pragma unroll
      for (int pp = 0; pp < 4; ++pp)
        acc[mf][pp] = __builtin_amdgcn_mfma_f32_16x16x32_bf16(
            aa[kb & 1][mf], bb[kb % 3][pp], acc[mf][pp], 0, 0, 0);
  }
}

// acc -> global fp32, layout [tc][b][head][256]
__device__ __forceinline__ void acc_to_global_f32(
    float* __restrict__ dst, const floatx4 acc[4][4],
    int l, int w, int b, int tt)
{
  int col = l & 15, quad = l >> 4;
#pragma unroll
  for (int mf = 0; mf < 4; ++mf)
#pragma unroll
    for (int r = 0; r < 4; ++r) {
      int m2 = mf * 16 + quad * 4 + r;
      size_t base = (((size_t)(tt * 16 + (m2 >> 2)) * 64 + b) * 4 + (m2 & 3)) * 256;
#pragma unroll
      for (int pp = 0; pp < 4; ++pp)
        dst[base + (w * 4 + pp) * 16 + col] = acc[mf][pp][r];
    }
}

// ---------------------------------------------------------------------------
// precompute: stage X once; two independent GEMMs off the same A tile
//   xw1 = X@W1a + (b1+cb) ;  kpw = X@Wd ;  kw2 = 2*(X.wkw) + cks
// ---------------------------------------------------------------------------
__device__ void precompute_block(
    int px, const float* __restrict__ x, const unsigned short* __restrict__ wpack,
    const float* __restrict__ ws,
    float* __restrict__ kw_c, float* __restrict__ xw1_c,
    float* __restrict__ kpw_c, int t0, char* smem)
{
  float* kwbuf = (float*)smem;                              // [64][4] fp32
  unsigned short* XS = (unsigned short*)(smem + 2048);      // [64][LDH] bf16

  int b  = px & 63;
  int tt = px >> 6;
  int tid = threadIdx.x;
  int l = tid & 63, w = tid >> 6;

  // stage X (64x256 fp32 -> bf16 LDS), coalesced
  const float4* xsrc = (const float4*)(x + (size_t)(b * SS + t0 + tt * 16) * NHH * DD);
#pragma unroll
  for (int i = 0; i < 16; ++i) {
    int f4 = i * 256 + tid;
    int r = f4 >> 6, c4 = f4 & 63;
    float4 v = xsrc[f4];
    ushort4 h;
    h.x = f2b(v.x); h.y = f2b(v.y); h.z = f2b(v.z); h.w = f2b(v.w);
    *(ushort4*)&XS[r * LDH + c4 * 4] = h;
  }
  __syncthreads();

  const short8* wpA = (const short8*)(wpack);               // W1a
  const short8* wpD = (const short8*)(wpack + 65536);       // Wd

  // kw partials: wave w covers cols [w*64, w*64+64), row = l, from XS
  {
    const float* wkw = ws + 197632;
    float part = 0.f;
    const unsigned short* trow = XS + l * LDH + w * 64;
#pragma unroll
    for (int j8 = 0; j8 < 8; ++j8) {
      short8 tv = *(const short8*)(trow + j8 * 8);
#pragma unroll
      for (int j = 0; j < 8; ++j)
        part = fmaf(b2f((unsigned short)tv[j]), wkw[w * 64 + j8 * 8 + j], part);
    }
    kwbuf[l * 4 + w] = part;
  }

  floatx4 acc[4][4];

  // GEMM 1: xw1 = X@W1a + (b1+cb) -> global fp32
  mfma_gemm4(XS, wpA, ws + 197888, acc, l, w);
  acc_to_global_f32(xw1_c, acc, l, w, b, tt);

  // GEMM 2: kpw = X@Wd -> global fp32
  mfma_gemm4(XS, wpD, nullptr, acc, l, w);
  acc_to_global_f32(kpw_c, acc, l, w, b, tt);

  __syncthreads();   // kwbuf complete
  if (tid < 64) {
    float s = kwbuf[tid * 4] + kwbuf[tid * 4 + 1] + kwbuf[tid * 4 + 2] + kwbuf[tid * 4 + 3]
            + ws[513];
    kw_c[((size_t)(tt * 16 + (tid >> 2)) * 64 + b) * 4 + (tid & 3)] = s;
  }
}

// ---------------------------------------------------------------------------
__device__ __forceinline__ float wave_reduce_sum(float x) {
#define DPPSTEP(ctrl, rmask)                                                   \
  {                                                                            \
    int _s = __builtin_amdgcn_update_dpp(0, __builtin_bit_cast(int, x),        \
                                         (ctrl), (rmask), 0xf, true);          \
    x += __builtin_bit_cast(float, _s);                                        \
  }
  DPPSTEP(0x111, 0xf)   // row_shr:1
  DPPSTEP(0x112, 0xf)   // row_shr:2
  DPPSTEP(0x114, 0xf)   // row_shr:4
  DPPSTEP(0x118, 0xf)   // row_shr:8
  DPPSTEP(0x142, 0xa)   // row_bcast15
  DPPSTEP(0x143, 0xc)   // row_bcast31
#undef DPPSTEP
  return __builtin_bit_cast(float, __builtin_amdgcn_readlane(__builtin_bit_cast(int, x), 63));
}

// ---------------------------------------------------------------------------
// seq: per wave = one (b, head i) chain. All tile data fp32; pointer-increment
// addressing; 4-slot prefetch; qw carried in 2x-prescaled domain.
// ---------------------------------------------------------------------------
__device__ void seq_block(
    const float* __restrict__ xw1_c, const float* __restrict__ kpw_c,
    const float* __restrict__ kw_c, float* __restrict__ ws,
    float* __restrict__ relu_u, int t0, int n)
{
  int b = blockIdx.x;
  int tid = threadIdx.x;
  int i = tid >> 6, l = tid & 63;

  float4 v2v = ((const float4*)ws)[l];    // prescaled x2
  float c2s = ws[512];
  float qw2 = ws[768 + b * 4 + i];

  struct Slot { float4 x, k0, k1, k2, k3, kw; };
  struct SP { const float4 *xp, *kp, *kw; };

  const float4* xw4 = (const float4*)xw1_c;
  const float4* kp4 = (const float4*)kpw_c;
  const float4* kw4 = (const float4*)kw_c;

  // base offsets (tc=0): xw float4 idx = tc*16384 + (b*4+i)*64 + l
  //                      kp  float4 idx = tc*16384 + b*256 + j*64 + l
  //                      kw  float4 idx = tc*64 + b
  SP p0 = { xw4 + (b * 4 + i) * 64 + l,             kp4 + b * 256 + l,             kw4 + b };
  SP p1 = { p0.xp + 16384, p0.kp + 16384, p0.kw + 64 };
  SP p2 = { p1.xp + 16384, p1.kp + 16384, p1.kw + 64 };
  SP p3 = { p2.xp + 16384, p2.kp + 16384, p2.kw + 64 };

  auto refill = [&](Slot& s, SP& p) {
    s.x  = *p.xp;
    s.k0 = p.kp[0];
    s.k1 = p.kp[64];
    s.k2 = p.kp[128];
    s.k3 = p.kp[192];
    s.kw = *p.kw;
    p.xp += 65536; p.kp += 65536; p.kw += 256;   // advance 4 timesteps
  };

  auto step = [&](Slot& s, int t) {
    // q_j = exp(tanh(qw + kw_j)); all in 2x-prescaled domain for the exp arg
    float r0 = __builtin_amdgcn_rcpf(__expf(qw2 + s.kw.x) + 1.f);
    float r1 = __builtin_amdgcn_rcpf(__expf(qw2 + s.kw.y) + 1.f);
    float r2 = __builtin_amdgcn_rcpf(__expf(qw2 + s.kw.z) + 1.f);
    float r3 = __builtin_amdgcn_rcpf(__expf(qw2 + s.kw.w) + 1.f);
    float q0 = __expf(fmaf(-2.f, r0, 1.f));
    float q1 = __expf(fmaf(-2.f, r1, 1.f));
    float q2 = __expf(fmaf(-2.f, r2, 1.f));
    float q3 = __expf(fmaf(-2.f, r3, 1.f));
    float inv = __builtin_amdgcn_rcpf((q0 + q1) + (q2 + q3));
    float4 a;
    a.x = fmaf(q0, s.k0.x, fmaf(q1, s.k1.x, fmaf(q2, s.k2.x, q3 * s.k3.x)));
    a.y = fmaf(q0, s.k0.y, fmaf(q1, s.k1.y, fmaf(q2, s.k2.y, q3 * s.k3.y)));
    a.z = fmaf(q0, s.k0.z, fmaf(q1, s.k1.z, fmaf(q2, s.k2.z, q3 * s.k3.z)));
    a.w = fmaf(q0, s.k0.w, fmaf(q1, s.k1.w, fmaf(q2, s.k2.w, q3 * s.k3.w)));
    float4 u;
    u.x = fmaf(a.x, inv, s.x.x); u.y = fmaf(a.y, inv, s.x.y);
    u.z = fmaf(a.z, inv, s.x.z); u.w = fmaf(a.w, inv, s.x.w);
    float4 rr;
    rr.x = fmaxf(u.x, 0.f); rr.y = fmaxf(u.y, 0.f);
    rr.z = fmaxf(u.z, 0.f); rr.w = fmaxf(u.w, 0.f);
    float d = fmaf(rr.x, v2v.x, rr.y * v2v.y) + fmaf(rr.z, v2v.z, rr.w * v2v.w);
    qw2 = wave_reduce_sum(d) + c2s;
    if (t0 + t == SS - 1)
      *(float4*)&relu_u[(size_t)(b * 4 + i) * 256 + l * 4] = rr;
  };

  Slot s0, s1, s2, s3;
  refill(s0, p0); refill(s1, p1); refill(s2, p2); refill(s3, p3);
  for (int t = 0; t < n; t += 4) {
    step(s0, t);     refill(s0, p0);
    step(s1, t + 1); refill(s1, p1);
    step(s2, t + 2); refill(s2, p2);
    step(s3, t + 3); refill(s3, p3);
  }
  if (l == 0) ws[768 + b * 4 + i] = qw2;
}

// ---------------------------------------------------------------------------
// Fused: blocks [0,64) = seq chunk (prev buffer), blocks [64,..) = precompute
// ---------------------------------------------------------------------------
__global__ __launch_bounds__(256, 1) void fused_kernel(
    const float* __restrict__ x, const unsigned short* __restrict__ wpack,
    float* kwB, float* xw1B, float* kpwB, int t0_pre,
    const float* kwA, const float* xw1A, const float* kpwA,
    int t0_seq, int n_seq,
    float* __restrict__ ws, float* __restrict__ relu_u)
{
  __shared__ __align__(16) char smem[2048 + 64 * LDH * 2];
  if (blockIdx.x < 64) {
    if (n_seq > 0) seq_block(xw1A, kpwA, kwA, ws, relu_u, t0_seq, n_seq);
    return;
  }
  precompute_block(blockIdx.x - 64, x, wpack, ws,
                   kwB, xw1B, kpwB, t0_pre, smem);
}

// ---------------------------------------------------------------------------
__global__ __launch_bounds__(256) void final_hidden_kernel(
    const float* __restrict__ relu_u, const float* __restrict__ W2,
    const float* __restrict__ b2, float* __restrict__ out)
{
  __shared__ float rs[256];
  int row = blockIdx.x;
  int tid = threadIdx.x;
  rs[tid] = relu_u[(size_t)row * 256 + tid];
  __syncthreads();
  float acc = b2[tid];
  for (int k = 0; k < 256; ++k) acc = fmaf(rs[k], W2[k * 256 + tid], acc);
  out[192 + (size_t)row * 256 + tid] = acc;
}

__global__ __launch_bounds__(256) void final_logits_kernel(
    const float* __restrict__ hf, const float* __restrict__ Wo,
    const float* __restrict__ bo, float* __restrict__ outp)
{
  __shared__ float r0[256], r1[256], r2[256];
  int b = blockIdx.x;
  int tid = threadIdx.x;
  float a0 = 0.f, a1 = 0.f, a2 = 0.f;
  for (int k = tid; k < 1024; k += 256) {
    float h = hf[(size_t)b * 1024 + k];
    a0 = fmaf(h, Wo[k * 3 + 0], a0);
    a1 = fmaf(h, Wo[k * 3 + 1], a1);
    a2 = fmaf(h, Wo[k * 3 + 2], a2);
  }
  r0[tid] = a0; r1[tid] = a1; r2[tid] = a2;
  __syncthreads();
  for (int s = 128; s; s >>= 1) {
    if (tid < s) { r0[tid] += r0[tid + s]; r1[tid] += r1[tid + s]; r2[tid] += r2[tid + s]; }
    __syncthreads();
  }
  if (tid == 0) {
    float l0 = r0[0] + bo[0], l1 = r1[0] + bo[1], l2 = r2[0] + bo[2];
    float m = fmaxf(l0, fmaxf(l1, l2));
    float lse = m + logf(expf(l0 - m) + expf(l1 - m) + expf(l2 - m));
    outp[b * 3 + 0] = l0 - lse;
    outp[b * 3 + 1] = l1 - lse;
    outp[b * 3 + 2] = l2 - lse;
  }
}

// ---------------------------------------------------------------------------
extern "C" void kernel_launch(void* const* d_in, const int* in_sizes, int n_in,
                              void* d_out, int out_size, void* d_ws, size_t ws_size,
                              hipStream_t stream)
{
  const float* x     = (const float*)d_in[0];
  const float* Wk    = (const float*)d_in[1];
  const float* bk    = (const float*)d_in[2];
  const float* Wq    = (const float*)d_in[3];
  const float* bq    = (const float*)d_in[4];
  const float* w_mlp = (const float*)d_in[5];
  const float* Wproj = (const float*)d_in[6];
  const float* bproj = (const float*)d_in[7];
  const float* W1    = (const float*)d_in[8];
  const float* b1    = (const float*)d_in[9];
  const float* W2    = (const float*)d_in[10];
  const float* b2    = (const float*)d_in[11];
  const float* Wo    = (const float*)d_in[12];
  const float* bo    = (const float*)d_in[13];
  float* out = (float*)d_out;
  float* ws  = (float*)d_ws;

  float* ru = ws + 1024;
  unsigned short* wpack = (unsigned short*)(ws + 66560);
  const size_t OFF_CH = 198144;                      // floats
  const long per_t = 256 + 2 * 65536;                // floats per timestep (all fp32)

  long ws_floats = (long)(ws_size / 4);
  long avail = ws_floats - (long)OFF_CH - 8L * per_t;  // slack for prefetch overrun

  int Tc = 128;
  while (Tc > 0 && 2L * Tc * per_t > avail) Tc -= 16;
  bool pipelined = (Tc >= 16);
  if (!pipelined) {
    Tc = 128;
    while (Tc > 16 && (long)Tc * per_t > avail) Tc -= 16;
  }

  float* bufA = ws + OFF_CH;
  float* bufB = pipelined ? bufA + (size_t)Tc * per_t : bufA;

  auto kw_of  = [&](float* base) { return base; };
  auto xw_of  = [&](float* base) { return base + (size_t)Tc * 256; };
  auto kpw_of = [&](float* base) { return base + (size_t)Tc * 256 + (size_t)Tc * 65536; };

  init1_kernel<<<513, 256, 0, stream>>>(Wk, Wproj, W1, Wq, bq, w_mlp, W2, b2, bk,
                                        ws, wpack);
  init2_kernel<<<257, 256, 0, stream>>>(Wk, W1, bproj, bk, w_mlp, b1, ws, wpack);

  int C = (SS + Tc - 1) / Tc;

  if (pipelined) {
    for (int r = 0; r <= C; ++r) {
      bool hasPre = (r < C);
      bool hasSeq = (r >= 1);
      int t0p = r * Tc;
      int np  = hasPre ? ((SS - t0p) < Tc ? (SS - t0p) : Tc) : 0;
      int t0s = (r - 1) * Tc;
      int ns  = hasSeq ? ((SS - t0s) < Tc ? (SS - t0s) : Tc) : 0;
      float* pB = ((r & 1) ? bufB : bufA);
      float* pA = (((r - 1) & 1) ? bufB : bufA);
      int grid = 64 + (hasPre ? 64 * (np / 16) : 0);
      fused_kernel<<<grid, 256, 0, stream>>>(
          x, wpack,
          kw_of(pB), xw_of(pB), kpw_of(pB), t0p,
          kw_of(pA), xw_of(pA), kpw_of(pA), t0s, ns,
          ws, ru);
    }
  } else {
    for (int c = 0; c < C; ++c) {
      int t0 = c * Tc;
      int n = (SS - t0) < Tc ? (SS - t0) : Tc;
      fused_kernel<<<64 + 64 * (n / 16), 256, 0, stream>>>(
          x, wpack,
          kw_of(bufA), xw_of(bufA), kpw_of(bufA), t0,
          kw_of(bufA), xw_of(bufA), kpw_of(bufA), 0, 0,
          ws, ru);
      fused_kernel<<<64, 256, 0, stream>>>(
          x, wpack,
          kw_of(bufA), xw_of(bufA), kpw_of(bufA), t0,
          kw_of(bufA), xw_of(bufA), kpw_of(bufA), t0, n,
          ws, ru);
    }
  }

  final_hidden_kernel<<<BB * NHH, 256, 0, stream>>>(ru, W2, b2, out);
  final_logits_kernel<<<BB, 256, 0, stream>>>(out + 192, Wo, bo, out);
}